// Round 1
// baseline (142.414 us; speedup 1.0000x reference)
//
#include <hip/hip_runtime.h>

// Maj3: out[b,o,h,w] = sum_{kh,c} sign( sum_{kw} x[b,c,h+kh-1,w+kw-1] * W[o,kw,kh,c] )
// x: (4,64,56,56) f32; W: (64,3,3,64) f32; out: (4,64,56,56) f32.
// Bit-exactness vs numpy required (integer output, threshold 1.36): no FMA
// contraction, same add order, sign(0)=0 handled by skipping fully-pad rows.

#define Bn 4
#define Cn 64
#define Hn 56
#define Wn 56
#define On 64
#define OG 8   // output channels per block (uniform per block -> scalar weight loads)

// Force a plain IEEE fp32 mul that cannot be contracted into v_fmac by the
// consumer add (empty asm barrier makes the product opaque to isel).
__device__ __forceinline__ float mulrn(float a, float b) {
    float p = a * b;
    asm volatile("" : "+v"(p));
    return p;
}

__global__ __launch_bounds__(256, 4)
void maj3_kernel(const float* __restrict__ x,
                 const float* __restrict__ wt,
                 float* __restrict__ out)
{
    const int lane = threadIdx.x & 63;
    const int wave = threadIdx.x >> 6;
    const int bh   = blockIdx.x * 4 + wave;   // 0..223, one (b,h) row per wave
    const int b    = bh / Hn;
    const int h    = bh - b * Hn;
    const int og   = blockIdx.y * OG;         // block-uniform o base

    const int wc   = lane;                    // pixel column; lanes >=56 inactive
    const bool act = wc < Wn;

    // Clamped tap addresses (never OOB) + per-tap validity for zero padding.
    const int c0 = min(max(wc - 1, 0), Wn - 1);
    const int c1 = min(wc, Wn - 1);
    const int c2 = min(wc + 1, Wn - 1);
    const bool f0 = (wc >= 1);
    const bool f1 = act;
    const bool f2 = (wc + 1 < Wn);

    int acc[OG];
    #pragma unroll
    for (int i = 0; i < OG; ++i) acc[i] = 0;

    int nvalid = 0;
    const float* xb = x + b * (Cn * Hn * Wn);

    for (int kh = 0; kh < 3; ++kh) {
        const int row = h + kh - 1;
        if (row < 0 || row >= Hn) continue;   // fully-pad row: sign(0)=0, skip
        ++nvalid;
        const float* xr = xb + row * Wn;
        #pragma unroll 4
        for (int c = 0; c < Cn; ++c) {
            const float* xc = xr + c * (Hn * Wn);
            const float v0 = xc[c0];
            const float v1 = xc[c1];
            const float v2 = xc[c2];
            const float x0 = f0 ? v0 : 0.0f;
            const float x1 = f1 ? v1 : 0.0f;
            const float x2 = f2 ? v2 : 0.0f;
            #pragma unroll
            for (int oo = 0; oo < OG; ++oo) {
                // W[o,kw,kh,c] = wt[o*576 + kw*192 + kh*64 + c]; address is
                // wave-uniform (blockIdx + loop counters) -> s_load path.
                const float* wp = wt + (og + oo) * (3 * 3 * Cn) + kh * Cn + c;
                const float p0 = mulrn(x0, wp[0 * 3 * Cn]);
                const float p1 = mulrn(x1, wp[1 * 3 * Cn]);
                const float p2 = mulrn(x2, wp[2 * 3 * Cn]);
                const float s  = (p0 + p1) + p2;   // same order as reference
                acc[oo] += (int)(__float_as_uint(s) >> 31);  // count negatives
            }
        }
    }

    if (act) {
        float* ob = out + ((b * On + og) * Hn + h) * Wn + wc;
        const float base = (float)(nvalid * Cn);
        #pragma unroll
        for (int oo = 0; oo < OG; ++oo)
            ob[oo * Hn * Wn] = base - 2.0f * (float)acc[oo];  // N - 2*negcount
    }
}

extern "C" void kernel_launch(void* const* d_in, const int* in_sizes, int n_in,
                              void* d_out, int out_size, void* d_ws, size_t ws_size,
                              hipStream_t stream) {
    const float* x  = (const float*)d_in[0];
    const float* wt = (const float*)d_in[1];
    float* o        = (float*)d_out;
    dim3 grid(56, 8);   // 56 row-blocks (4 rows each) x 8 o-groups of 8
    maj3_kernel<<<grid, dim3(256), 0, stream>>>(x, wt, o);
}